// Round 2
// baseline (12086.015 us; speedup 1.0000x reference)
//
#include <hip/hip_runtime.h>

#define NU 80000
#define NI 40000
#define DD 128
#define NNZ_E 2000000
#define EPSN 1e-12f
#define BWROWS 256
#define NBU 313   // ceil(NU/256)
#define NBI 157   // ceil(NI/256)
#define NBPAD 320
#define BSTRIDE 336  // base array row stride (NBPAD+16)
#define BIN_E 8192

struct EdgePtrs { const int* rows[4]; const int* cols[4]; const float* vals[4]; };
struct GatherPtrs {
  const void* xt[2][4];   // [dir][behavior] table: dir0 = item-side (U-gather), dir1 = user-side
  float* out[2][4];       // l2n slices
  float* dup[2][4];       // raw u0..u2 / i0..i2 slots (null for b=3)
  int isbf[2];
};

__device__ inline unsigned short f2bf(float f) {
  unsigned int u = __float_as_uint(f);
  u += 0x7FFFu + ((u >> 16) & 1u);   // RNE
  return (unsigned short)(u >> 16);
}

__global__ __launch_bounds__(256) void conv_k(const float* __restrict__ src,
                                              unsigned short* __restrict__ dst, int n4) {
  int stride = blockDim.x * gridDim.x;
  for (int i = blockIdx.x * blockDim.x + threadIdx.x; i < n4; i += stride) {
    float4 f = ((const float4*)src)[i];
    ushort4 h;
    h.x = f2bf(f.x); h.y = f2bf(f.y); h.z = f2bf(f.z); h.w = f2bf(f.w);
    ((ushort4*)dst)[i] = h;
  }
}

// -------- bucket histogram (both dirs), LDS-local then flush --------
__global__ __launch_bounds__(256) void hist_k(EdgePtrs ep, int b0, int* cntA) {
  int j = blockIdx.y;
  const int* __restrict__ rows = ep.rows[b0 + j];
  const int* __restrict__ cols = ep.cols[b0 + j];
  __shared__ int lh[NBU + NBI];
  for (int i = threadIdx.x; i < NBU + NBI; i += blockDim.x) lh[i] = 0;
  __syncthreads();
  int stride = blockDim.x * gridDim.x;
  for (int e = blockIdx.x * blockDim.x + threadIdx.x; e < NNZ_E; e += stride) {
    atomicAdd(&lh[rows[e] >> 8], 1);
    atomicAdd(&lh[NBU + (cols[e] >> 8)], 1);
  }
  __syncthreads();
  int* cu = cntA + (j * 2 + 0) * NBPAD;
  int* ci = cntA + (j * 2 + 1) * NBPAD;
  for (int i = threadIdx.x; i < NBU + NBI; i += blockDim.x) {
    int v = lh[i];
    if (v) {
      if (i < NBU) atomicAdd(&cu[i], v);
      else atomicAdd(&ci[i - NBU], v);
    }
  }
}

// exclusive scan over <=512 values, blockDim must be 512
__device__ inline int scan_excl512(int v, int* wsums) {
  int t = threadIdx.x, lane = t & 63, w = t >> 6;
  int s = v;
  #pragma unroll
  for (int off = 1; off < 64; off <<= 1) {
    int x = __shfl_up(s, off);
    if (lane >= off) s += x;
  }
  if (lane == 63) wsums[w] = s;
  __syncthreads();
  if (t == 0) {
    int run = 0;
    for (int k = 0; k < 8; k++) { int x = wsums[k]; wsums[k] = run; run += x; }
    wsums[8] = run;
  }
  __syncthreads();
  return wsums[w] + s - v;
}

__global__ __launch_bounds__(512) void scanb_k(const int* cntA, int* baseA, int* gcurA) {
  __shared__ int wsums[9];
  int a = blockIdx.x;
  int dir = a & 1;
  int n = dir ? NBI : NBU;
  const int* cnt = cntA + a * NBPAD;
  int* base = baseA + a * BSTRIDE;
  int* gcur = gcurA + a * NBPAD;
  int t = threadIdx.x;
  int v = (t < n) ? cnt[t] : 0;
  int ex = scan_excl512(v, wsums);
  if (t < n) { base[t] = ex; gcur[t] = ex; }
  if (t == 0) base[n] = wsums[8];
}

// -------- binning: LDS counting-sort of 8192-edge chunks, coalesced flush --------
__global__ __launch_bounds__(512) void bin_k(EdgePtrs ep, int b0, int* gcurA, int2* binned) {
  __shared__ int2 stage[BIN_E];     // 64 KB
  __shared__ int lh[NBPAD], lscan[NBPAD], lcur[NBPAD], gpos[NBPAD];
  __shared__ int wsums[9];
  int dir = blockIdx.y, j = blockIdx.z, b = b0 + j;
  int NB = dir ? NBI : NBU;
  const int* __restrict__ dst = dir ? ep.cols[b] : ep.rows[b];
  const int* __restrict__ src = dir ? ep.rows[b] : ep.cols[b];
  const float* __restrict__ vals = ep.vals[b];
  int* gcur = gcurA + (j * 2 + dir) * NBPAD;
  int2* out = binned + ((size_t)j * 2 + dir) * NNZ_E;
  int t = threadIdx.x;
  int e0 = blockIdx.x * BIN_E;
  int nh = min(BIN_E, NNZ_E - e0);
  for (int i = t; i < NBPAD; i += 512) lh[i] = 0;
  __syncthreads();
  for (int i = t; i < nh; i += 512) atomicAdd(&lh[dst[e0 + i] >> 8], 1);
  __syncthreads();
  int v = (t < NB) ? lh[t] : 0;
  int ex = scan_excl512(v, wsums);
  if (t < NB) { lscan[t] = ex; lcur[t] = ex; gpos[t] = atomicAdd(&gcur[t], v); }
  __syncthreads();
  for (int i = t; i < nh; i += 512) {
    int d = dst[e0 + i], s = src[e0 + i];
    int k = d >> 8;
    int pos = atomicAdd(&lcur[k], 1);
    stage[pos] = make_int2(s | ((d & 255) << 17), __float_as_int(vals[e0 + i]));
  }
  __syncthreads();
  int w = t >> 6, lane = t & 63;
  for (int k = w; k < NB; k += 8) {
    int c = lh[k];
    const int2* sp = stage + lscan[k];
    int2* gp = out + gpos[k];
    for (int i = lane; i < c; i += 64) gp[i] = sp[i];
  }
}

// -------- fused gather: one bucket per block, LDS f32 accumulator + colsq --------
__global__ __launch_bounds__(1024) void gather_k(GatherPtrs gp, int b0,
                                                 const int* baseA, const int2* binned,
                                                 float* colsums) {
  __shared__ float acc[BWROWS * DD];  // 128 KB
  __shared__ float csq[DD];
  int gb = blockIdx.x;
  int j = gb / (NBU + NBI);
  int r = gb - j * (NBU + NBI);
  int dir = (r >= NBU) ? 1 : 0;
  int k = dir ? (r - NBU) : r;
  int b = b0 + j;
  int n = dir ? NI : NU;
  const int* base = baseA + (j * 2 + dir) * BSTRIDE;
  const int2* __restrict__ bb = binned + ((size_t)j * 2 + dir) * NNZ_E;
  int t = threadIdx.x;
  float4 z = make_float4(0.f, 0.f, 0.f, 0.f);
  #pragma unroll
  for (int q = 0; q < 8; q++) ((float4*)acc)[t + q * 1024] = z;
  if (t < DD) csq[t] = 0.f;
  __syncthreads();
  int beg = base[k], end = base[k + 1];
  int g = t >> 5, lane = t & 31;
  const void* xt = gp.xt[dir][b];
  if (gp.isbf[dir]) {
    const ushort4* __restrict__ x4 = (const ushort4*)xt;
    for (int e = beg + g; e < end; e += 32) {
      int2 p = bb[e];
      int s = p.x & 0x1FFFF, ld = (p.x >> 17) & 255;
      float v = __int_as_float(p.y);
      ushort4 h = x4[(size_t)s * 32 + lane];
      float* ar = acc + (ld << 7) + (lane << 2);
      atomicAdd(ar + 0, v * __uint_as_float((unsigned int)h.x << 16));
      atomicAdd(ar + 1, v * __uint_as_float((unsigned int)h.y << 16));
      atomicAdd(ar + 2, v * __uint_as_float((unsigned int)h.z << 16));
      atomicAdd(ar + 3, v * __uint_as_float((unsigned int)h.w << 16));
    }
  } else {
    const float4* __restrict__ x4 = (const float4*)xt;
    for (int e = beg + g; e < end; e += 32) {
      int2 p = bb[e];
      int s = p.x & 0x1FFFF, ld = (p.x >> 17) & 255;
      float v = __int_as_float(p.y);
      float4 xv = x4[(size_t)s * 32 + lane];
      float* ar = acc + (ld << 7) + (lane << 2);
      atomicAdd(ar + 0, v * xv.x);
      atomicAdd(ar + 1, v * xv.y);
      atomicAdd(ar + 2, v * xv.z);
      atomicAdd(ar + 3, v * xv.w);
    }
  }
  __syncthreads();
  int row0 = k << 8;
  float* outp = gp.out[dir][b];
  float* dupp = gp.dup[dir][b];
  float4 sq = z;
  #pragma unroll
  for (int q = 0; q < 8; q++) {
    int idx = t + q * 1024;
    int row = idx >> 5, c4 = idx & 31;
    if (row0 + row < n) {
      float4 vv = ((float4*)acc)[idx];
      ((float4*)outp)[(size_t)(row0 + row) * 32 + c4] = vv;
      if (dupp) ((float4*)dupp)[(size_t)(row0 + row) * 32 + c4] = vv;
      sq.x += vv.x * vv.x; sq.y += vv.y * vv.y; sq.z += vv.z * vv.z; sq.w += vv.w * vv.w;
    }
  }
  int c4 = t & 31;
  atomicAdd(&csq[c4 * 4 + 0], sq.x);
  atomicAdd(&csq[c4 * 4 + 1], sq.y);
  atomicAdd(&csq[c4 * 4 + 2], sq.z);
  atomicAdd(&csq[c4 * 4 + 3], sq.w);
  __syncthreads();
  if (t < DD) atomicAdd(&colsums[(dir * 4 + b) * DD + t], csq[t]);
}

// ---------------- mean(4 slices) @ W, sigmoid ----------------
__global__ __launch_bounds__(256) void gemm_sig_k(const float* __restrict__ x, size_t sstride,
                                                  const float* __restrict__ W, float* __restrict__ out,
                                                  int n) {
  __shared__ float wl[DD * DD];
  __shared__ float rl[8][DD];
  for (int i = threadIdx.x; i < DD * DD / 4; i += blockDim.x)
    ((float4*)wl)[i] = ((const float4*)W)[i];
  int c = threadIdx.x & 127;
  int g = threadIdx.x >> 7;
  int row0 = blockIdx.x * 64;
  for (int rr = 0; rr < 64; rr += 8) {
    int rbase = row0 + rr;
    __syncthreads();
    for (int i = threadIdx.x; i < 8 * DD; i += blockDim.x) {
      int lr = i >> 7, lc = i & 127;
      int r = rbase + lr;
      float m = 0.f;
      if (r < n) {
        size_t off = (size_t)r * DD + lc;
        m = 0.25f * (x[off] + x[off + sstride] + x[off + 2 * sstride] + x[off + 3 * sstride]);
      }
      rl[lr][lc] = m;
    }
    __syncthreads();
    float acc0 = 0.f, acc1 = 0.f, acc2 = 0.f, acc3 = 0.f;
    #pragma unroll 4
    for (int k = 0; k < DD; k++) {
      float wv = wl[k * DD + c];
      acc0 += rl[g * 4 + 0][k] * wv;
      acc1 += rl[g * 4 + 1][k] * wv;
      acc2 += rl[g * 4 + 2][k] * wv;
      acc3 += rl[g * 4 + 3][k] * wv;
    }
    float accs[4] = {acc0, acc1, acc2, acc3};
    for (int jj = 0; jj < 4; jj++) {
      int r = rbase + g * 4 + jj;
      if (r < n) out[(size_t)r * DD + c] = 1.f / (1.f + __expf(-accs[jj]));
    }
  }
}

__global__ void inv_k(const float* __restrict__ sums, float* __restrict__ inv, int n) {
  int i = blockIdx.x * blockDim.x + threadIdx.x;
  if (i < n) inv[i] = 1.f / fmaxf(sqrtf(sums[i]), EPSN);
}

__global__ __launch_bounds__(256) void scale_k(float* __restrict__ base, size_t slice_f4,
                                               const float* __restrict__ inv) {
  int b = blockIdx.y;
  float4* b4 = (float4*)base + (size_t)b * slice_f4;
  const float4* inv4 = (const float4*)inv + (size_t)b * 32;
  size_t stride = (size_t)blockDim.x * gridDim.x;
  for (size_t i = (size_t)blockIdx.x * blockDim.x + threadIdx.x; i < slice_f4; i += stride) {
    float4 s = inv4[i & 31];
    float4 v = b4[i];
    v.x *= s.x; v.y *= s.y; v.z *= s.z; v.w *= s.w;
    b4[i] = v;
  }
}

// ---------------- host ----------------
extern "C" void kernel_launch(void* const* d_in, const int* in_sizes, int n_in,
                              void* d_out, int out_size, void* d_ws, size_t ws_size,
                              hipStream_t stream) {
  const float* user_emb = (const float*)d_in[0];
  const float* item_emb = (const float*)d_in[1];
  const float* uu[4] = {(const float*)d_in[2], (const float*)d_in[4], (const float*)d_in[6], user_emb};
  const float* ii[4] = {(const float*)d_in[3], (const float*)d_in[5], (const float*)d_in[7], item_emb};
  const float* u_w = (const float*)d_in[8];
  const float* i_w = (const float*)d_in[9];
  EdgePtrs ep;
  for (int b = 0; b < 4; b++) {
    ep.rows[b] = (const int*)d_in[10 + 3 * b];
    ep.cols[b] = (const int*)d_in[11 + 3 * b];
    ep.vals[b] = (const float*)d_in[12 + 3 * b];
  }

  float* out = (float*)d_out;
  float* user_out = out;
  float* item_out = out + (size_t)NU * DD;
  float* l2nU = item_out + (size_t)NI * DD;
  float* l2nI = l2nU + (size_t)4 * NU * DD;
  float* u_slot[3];
  float* i_slot[3];
  {
    float* p = l2nI + (size_t)4 * NI * DD;
    for (int b = 0; b < 3; b++) {
      u_slot[b] = p; p += (size_t)NU * DD;
      i_slot[b] = p; p += (size_t)NI * DD;
    }
  }

  const size_t item_bf_sz = (size_t)4 * NI * DD * 2;   // ~41 MB
  const size_t user_bf_sz = (size_t)4 * NU * DD * 2;   // ~82 MB
  const size_t bin_slot_sz = (size_t)2 * NNZ_E * 8;    // 32 MB per behavior slot
  const size_t smalls = 256 * 1024;

  int batchB = 1; bool bfI = false, bfU = false;
  if (ws_size >= 4 * bin_slot_sz + item_bf_sz + user_bf_sz + smalls) { batchB = 4; bfI = bfU = true; }
  else if (ws_size >= bin_slot_sz + item_bf_sz + user_bf_sz + smalls) { batchB = 1; bfI = bfU = true; }
  else if (ws_size >= bin_slot_sz + item_bf_sz + smalls) { batchB = 1; bfI = true; }

  char* w = (char*)d_ws;
  auto alloc = [&](size_t bytes) {
    char* r = w;
    w += (bytes + 255) & ~(size_t)255;
    return r;
  };
  int2* binned = (int2*)alloc((size_t)batchB * bin_slot_sz);
  unsigned short* itemB = bfI ? (unsigned short*)alloc(item_bf_sz) : nullptr;
  unsigned short* userB = bfU ? (unsigned short*)alloc(user_bf_sz) : nullptr;
  int* cntA = (int*)alloc(4 * 2 * NBPAD * 4);
  int* baseA = (int*)alloc(4 * 2 * BSTRIDE * 4);
  int* gcurA = (int*)alloc(4 * 2 * NBPAD * 4);
  float* colsums = (float*)alloc(8 * DD * 4);
  float* invs = (float*)alloc(8 * DD * 4);

  if (bfI)
    for (int b = 0; b < 4; b++)
      conv_k<<<512, 256, 0, stream>>>(ii[b], itemB + (size_t)b * NI * DD, NI * DD / 4);
  if (bfU)
    for (int b = 0; b < 4; b++)
      conv_k<<<512, 256, 0, stream>>>(uu[b], userB + (size_t)b * NU * DD, NU * DD / 4);

  GatherPtrs gp;
  gp.isbf[0] = bfI ? 1 : 0;
  gp.isbf[1] = bfU ? 1 : 0;
  for (int b = 0; b < 4; b++) {
    gp.xt[0][b] = bfI ? (const void*)(itemB + (size_t)b * NI * DD) : (const void*)ii[b];
    gp.xt[1][b] = bfU ? (const void*)(userB + (size_t)b * NU * DD) : (const void*)uu[b];
    gp.out[0][b] = l2nU + (size_t)b * NU * DD;
    gp.out[1][b] = l2nI + (size_t)b * NI * DD;
    gp.dup[0][b] = (b < 3) ? u_slot[b] : nullptr;
    gp.dup[1][b] = (b < 3) ? i_slot[b] : nullptr;
  }

  hipMemsetAsync(colsums, 0, 8 * DD * 4, stream);
  const int nchunks = (NNZ_E + BIN_E - 1) / BIN_E;  // 245
  for (int b0 = 0; b0 < 4; b0 += batchB) {
    hipMemsetAsync(cntA, 0, (size_t)batchB * 2 * NBPAD * 4, stream);
    hist_k<<<dim3(256, batchB), 256, 0, stream>>>(ep, b0, cntA);
    scanb_k<<<batchB * 2, 512, 0, stream>>>(cntA, baseA, gcurA);
    bin_k<<<dim3(nchunks, 2, batchB), 512, 0, stream>>>(ep, b0, gcurA, binned);
    gather_k<<<batchB * (NBU + NBI), 1024, 0, stream>>>(gp, b0, baseA, binned, colsums);
  }

  gemm_sig_k<<<NU / 64, 256, 0, stream>>>(l2nU, (size_t)NU * DD, u_w, user_out, NU);
  gemm_sig_k<<<NI / 64, 256, 0, stream>>>(l2nI, (size_t)NI * DD, i_w, item_out, NI);

  inv_k<<<4, 256, 0, stream>>>(colsums, invs, 8 * DD);
  scale_k<<<dim3(1024, 4), 256, 0, stream>>>(l2nU, (size_t)NU * 32, invs);
  scale_k<<<dim3(1024, 4), 256, 0, stream>>>(l2nI, (size_t)NI * 32, invs + 4 * DD);
}

// Round 3
// 2008.966 us; speedup vs baseline: 6.0160x; 6.0160x over previous
//
#include <hip/hip_runtime.h>

#define NU 80000
#define NI 40000
#define DD 128
#define NNZ_E 2000000
#define EPSN 1e-12f
#define BWROWS 256
#define NBU 313   // ceil(NU/256)
#define NBI 157   // ceil(NI/256)
#define NBPAD 320
#define BIN_E 8192
#define S2CAP 16384

struct EdgePtrs { const int* rows[4]; const int* cols[4]; const float* vals[4]; };

__device__ inline unsigned short f2bf(float f) {
  unsigned int u = __float_as_uint(f);
  u += 0x7FFFu + ((u >> 16) & 1u);   // RNE
  return (unsigned short)(u >> 16);
}

__global__ __launch_bounds__(256) void conv_k(const float* __restrict__ src,
                                              unsigned short* __restrict__ dst, int n4) {
  int stride = blockDim.x * gridDim.x;
  for (int i = blockIdx.x * blockDim.x + threadIdx.x; i < n4; i += stride) {
    float4 f = ((const float4*)src)[i];
    ushort4 h;
    h.x = f2bf(f.x); h.y = f2bf(f.y); h.z = f2bf(f.z); h.w = f2bf(f.w);
    ((ushort4*)dst)[i] = h;
  }
}

// -------- exact-row histogram, all 4 behaviors --------
__global__ __launch_bounds__(256) void hist_k(EdgePtrs ep, int* cntU, int* cntI) {
  int b = blockIdx.y;
  const int* __restrict__ rows = ep.rows[b];
  const int* __restrict__ cols = ep.cols[b];
  int* cu = cntU + (size_t)b * NU;
  int* ci = cntI + (size_t)b * NI;
  int stride = blockDim.x * gridDim.x;
  for (int e = blockIdx.x * blockDim.x + threadIdx.x; e < NNZ_E; e += stride) {
    atomicAdd(&cu[rows[e]], 1);
    atomicAdd(&ci[cols[e]], 1);
  }
}

// -------- exclusive scan, one block per (behavior,dir) array --------
__global__ __launch_bounds__(1024) void scan8_k(const int* cntU, const int* cntI,
                                                int* rpU, int* rpI) {
  __shared__ int wsum[17];
  int a = blockIdx.x;          // 0..7
  int b = a >> 1, dir = a & 1;
  int n = dir ? NI : NU;
  const int* cnt = dir ? (cntI + (size_t)b * NI) : (cntU + (size_t)b * NU);
  int* rp = dir ? (rpI + (size_t)b * (NI + 1)) : (rpU + (size_t)b * (NU + 1));
  int t = threadIdx.x;
  int lane = t & 63, w = t >> 6;
  int carry = 0;
  for (int base = 0; base < n; base += 1024) {
    int i = base + t;
    int v = (i < n) ? cnt[i] : 0;
    int s = v;
    #pragma unroll
    for (int off = 1; off < 64; off <<= 1) {
      int x = __shfl_up(s, off);
      if (lane >= off) s += x;
    }
    if (lane == 63) wsum[w] = s;
    __syncthreads();
    if (t == 0) {
      int run = 0;
      for (int k = 0; k < 16; k++) { int x = wsum[k]; wsum[k] = run; run += x; }
      wsum[16] = run;
    }
    __syncthreads();
    if (i < n) rp[i] = carry + wsum[w] + (s - v);
    carry += wsum[16];
    __syncthreads();
  }
  if (t == 0) rp[n] = carry;
}

// -------- init bucket cursors from rp[k*256] --------
__global__ void initg_k(const int* rpU, const int* rpI, int* gcurA, int b0, int batchB) {
  int i = blockIdx.x * blockDim.x + threadIdx.x;
  int tot = batchB * 2 * NBPAD;
  if (i >= tot) return;
  int a = i / NBPAD, k = i - a * NBPAD;
  int j = a >> 1, dir = a & 1, b = b0 + j;
  const int* rp = dir ? (rpI + (size_t)b * (NI + 1)) : (rpU + (size_t)b * (NU + 1));
  int n = dir ? NI : NU;
  int idx = k * BWROWS;
  if (idx > n) idx = n;
  gcurA[i] = rp[idx];
}

// -------- pass 1: counting-sort chunks by bucket, coalesced flush --------
__global__ __launch_bounds__(512) void bin_k(EdgePtrs ep, int b0, int* gcurA, int2* binned) {
  __shared__ int2 stage[BIN_E];     // 64 KB
  __shared__ int lh[NBPAD], lscan[NBPAD], lcur[NBPAD], gpos[NBPAD];
  __shared__ int wsums[9];
  int dir = blockIdx.y, j = blockIdx.z, b = b0 + j;
  int NB = dir ? NBI : NBU;
  const int* __restrict__ dst = dir ? ep.cols[b] : ep.rows[b];
  const int* __restrict__ src = dir ? ep.rows[b] : ep.cols[b];
  const float* __restrict__ vals = ep.vals[b];
  int* gcur = gcurA + (j * 2 + dir) * NBPAD;
  int2* out = binned + ((size_t)j * 2 + dir) * NNZ_E;
  int t = threadIdx.x;
  int e0 = blockIdx.x * BIN_E;
  int nh = min(BIN_E, NNZ_E - e0);
  for (int i = t; i < NBPAD; i += 512) lh[i] = 0;
  __syncthreads();
  for (int i = t; i < nh; i += 512) atomicAdd(&lh[dst[e0 + i] >> 8], 1);
  __syncthreads();
  {
    int lane = t & 63, w = t >> 6;
    int v = (t < NB) ? lh[t] : 0;
    int s = v;
    #pragma unroll
    for (int off = 1; off < 64; off <<= 1) {
      int x = __shfl_up(s, off);
      if (lane >= off) s += x;
    }
    if (lane == 63) wsums[w] = s;
    __syncthreads();
    if (t == 0) {
      int run = 0;
      for (int k = 0; k < 8; k++) { int x = wsums[k]; wsums[k] = run; run += x; }
      wsums[8] = run;
    }
    __syncthreads();
    int ex = wsums[w] + s - v;
    if (t < NB) { lscan[t] = ex; lcur[t] = ex; gpos[t] = atomicAdd(&gcur[t], v); }
  }
  __syncthreads();
  for (int i = t; i < nh; i += 512) {
    int d = dst[e0 + i], s = src[e0 + i];
    int k = d >> 8;
    int pos = atomicAdd(&lcur[k], 1);
    stage[pos] = make_int2(s | ((d & 255) << 17), __float_as_int(vals[e0 + i]));
  }
  __syncthreads();
  int w = t >> 6, lane = t & 63;
  for (int k = w; k < NB; k += 8) {
    int c = lh[k];
    const int2* sp = stage + lscan[k];
    int2* gp = out + gpos[k];
    for (int i = lane; i < c; i += 64) gp[i] = sp[i];
  }
}

// -------- pass 2: in-place exact-row sort within each bucket --------
__global__ __launch_bounds__(512) void sort2_k(const int* rpU, const int* rpI, int b0, int2* binned) {
  __shared__ int2 stage[S2CAP];   // 128 KB
  __shared__ int lcur[257];
  int gb = blockIdx.x;
  int j = gb / (NBU + NBI);
  int r = gb - j * (NBU + NBI);
  int dir = (r >= NBU) ? 1 : 0;
  int k = dir ? (r - NBU) : r;
  int b = b0 + j;
  int n = dir ? NI : NU;
  const int* rp = dir ? (rpI + (size_t)b * (NI + 1)) : (rpU + (size_t)b * (NU + 1));
  int2* bb = binned + ((size_t)j * 2 + dir) * NNZ_E;
  int row0 = k << 8;
  int nrows = min(BWROWS, n - row0);
  int base0 = rp[row0];
  int tot = rp[row0 + nrows] - base0;
  int t = threadIdx.x;
  if (t <= nrows) lcur[t] = rp[row0 + t] - base0;
  __syncthreads();
  for (int i = t; i < tot; i += 512) {
    int2 p = bb[base0 + i];
    int ld = (p.x >> 17) & 255;
    int pos = atomicAdd(&lcur[ld], 1);
    stage[pos] = make_int2(p.x & 0x1FFFF, p.y);
  }
  __syncthreads();
  for (int i = t; i < tot; i += 512) bb[base0 + i] = stage[i];
}

// -------- gather SpMM: one 32-lane group per dst row, register acc --------
__global__ __launch_bounds__(256) void gather_k(const int* __restrict__ rp, const int2* __restrict__ pairs,
                                                const void* __restrict__ xt, int isbf,
                                                float* __restrict__ out1, float* __restrict__ out2,
                                                int nrows) {
  int gid = blockIdx.x * 8 + (threadIdx.x >> 5);
  int lane = threadIdx.x & 31;
  int tot = gridDim.x * 8;
  for (int r = gid; r < nrows; r += tot) {
    int beg = rp[r], end = rp[r + 1];
    float4 a0 = make_float4(0.f, 0.f, 0.f, 0.f);
    float4 a1 = make_float4(0.f, 0.f, 0.f, 0.f);
    int e = beg;
    if (isbf) {
      const ushort4* __restrict__ x4 = (const ushort4*)xt;
      for (; e + 3 < end; e += 4) {
        int2 p0 = pairs[e], p1 = pairs[e + 1], p2 = pairs[e + 2], p3 = pairs[e + 3];
        ushort4 h0 = x4[(size_t)p0.x * 32 + lane];
        ushort4 h1 = x4[(size_t)p1.x * 32 + lane];
        ushort4 h2 = x4[(size_t)p2.x * 32 + lane];
        ushort4 h3 = x4[(size_t)p3.x * 32 + lane];
        float v0 = __int_as_float(p0.y), v1 = __int_as_float(p1.y);
        float v2 = __int_as_float(p2.y), v3 = __int_as_float(p3.y);
        a0.x += v0 * __uint_as_float((unsigned)h0.x << 16);
        a0.y += v0 * __uint_as_float((unsigned)h0.y << 16);
        a0.z += v0 * __uint_as_float((unsigned)h0.z << 16);
        a0.w += v0 * __uint_as_float((unsigned)h0.w << 16);
        a1.x += v1 * __uint_as_float((unsigned)h1.x << 16);
        a1.y += v1 * __uint_as_float((unsigned)h1.y << 16);
        a1.z += v1 * __uint_as_float((unsigned)h1.z << 16);
        a1.w += v1 * __uint_as_float((unsigned)h1.w << 16);
        a0.x += v2 * __uint_as_float((unsigned)h2.x << 16);
        a0.y += v2 * __uint_as_float((unsigned)h2.y << 16);
        a0.z += v2 * __uint_as_float((unsigned)h2.z << 16);
        a0.w += v2 * __uint_as_float((unsigned)h2.w << 16);
        a1.x += v3 * __uint_as_float((unsigned)h3.x << 16);
        a1.y += v3 * __uint_as_float((unsigned)h3.y << 16);
        a1.z += v3 * __uint_as_float((unsigned)h3.z << 16);
        a1.w += v3 * __uint_as_float((unsigned)h3.w << 16);
      }
      for (; e < end; e++) {
        int2 p = pairs[e];
        ushort4 h = x4[(size_t)p.x * 32 + lane];
        float v = __int_as_float(p.y);
        a0.x += v * __uint_as_float((unsigned)h.x << 16);
        a0.y += v * __uint_as_float((unsigned)h.y << 16);
        a0.z += v * __uint_as_float((unsigned)h.z << 16);
        a0.w += v * __uint_as_float((unsigned)h.w << 16);
      }
    } else {
      const float4* __restrict__ x4 = (const float4*)xt;
      for (; e + 3 < end; e += 4) {
        int2 p0 = pairs[e], p1 = pairs[e + 1], p2 = pairs[e + 2], p3 = pairs[e + 3];
        float4 x0 = x4[(size_t)p0.x * 32 + lane];
        float4 x1 = x4[(size_t)p1.x * 32 + lane];
        float4 x2 = x4[(size_t)p2.x * 32 + lane];
        float4 x3 = x4[(size_t)p3.x * 32 + lane];
        float v0 = __int_as_float(p0.y), v1 = __int_as_float(p1.y);
        float v2 = __int_as_float(p2.y), v3 = __int_as_float(p3.y);
        a0.x += v0 * x0.x; a0.y += v0 * x0.y; a0.z += v0 * x0.z; a0.w += v0 * x0.w;
        a1.x += v1 * x1.x; a1.y += v1 * x1.y; a1.z += v1 * x1.z; a1.w += v1 * x1.w;
        a0.x += v2 * x2.x; a0.y += v2 * x2.y; a0.z += v2 * x2.z; a0.w += v2 * x2.w;
        a1.x += v3 * x3.x; a1.y += v3 * x3.y; a1.z += v3 * x3.z; a1.w += v3 * x3.w;
      }
      for (; e < end; e++) {
        int2 p = pairs[e];
        float4 xv = x4[(size_t)p.x * 32 + lane];
        float v = __int_as_float(p.y);
        a0.x += v * xv.x; a0.y += v * xv.y; a0.z += v * xv.z; a0.w += v * xv.w;
      }
    }
    float4 res = make_float4(a0.x + a1.x, a0.y + a1.y, a0.z + a1.z, a0.w + a1.w);
    ((float4*)out1)[(size_t)r * 32 + lane] = res;
    if (out2) ((float4*)out2)[(size_t)r * 32 + lane] = res;
  }
}

// ---------------- mean(4 slices) @ W, sigmoid ----------------
__global__ __launch_bounds__(256) void gemm_sig_k(const float* __restrict__ x, size_t sstride,
                                                  const float* __restrict__ W, float* __restrict__ out,
                                                  int n) {
  __shared__ float wl[DD * DD];
  __shared__ float rl[8][DD];
  for (int i = threadIdx.x; i < DD * DD / 4; i += blockDim.x)
    ((float4*)wl)[i] = ((const float4*)W)[i];
  int c = threadIdx.x & 127;
  int g = threadIdx.x >> 7;
  int row0 = blockIdx.x * 64;
  for (int rr = 0; rr < 64; rr += 8) {
    int rbase = row0 + rr;
    __syncthreads();
    for (int i = threadIdx.x; i < 8 * DD; i += blockDim.x) {
      int lr = i >> 7, lc = i & 127;
      int r = rbase + lr;
      float m = 0.f;
      if (r < n) {
        size_t off = (size_t)r * DD + lc;
        m = 0.25f * (x[off] + x[off + sstride] + x[off + 2 * sstride] + x[off + 3 * sstride]);
      }
      rl[lr][lc] = m;
    }
    __syncthreads();
    float acc0 = 0.f, acc1 = 0.f, acc2 = 0.f, acc3 = 0.f;
    #pragma unroll 4
    for (int k = 0; k < DD; k++) {
      float wv = wl[k * DD + c];
      acc0 += rl[g * 4 + 0][k] * wv;
      acc1 += rl[g * 4 + 1][k] * wv;
      acc2 += rl[g * 4 + 2][k] * wv;
      acc3 += rl[g * 4 + 3][k] * wv;
    }
    float accs[4] = {acc0, acc1, acc2, acc3};
    for (int jj = 0; jj < 4; jj++) {
      int r = rbase + g * 4 + jj;
      if (r < n) out[(size_t)r * DD + c] = 1.f / (1.f + __expf(-accs[jj]));
    }
  }
}

// ---------------- column sum-of-squares / normalize ----------------
__global__ __launch_bounds__(256) void colsq_k(const float* __restrict__ base, size_t sstride, int n,
                                               float* __restrict__ sums) {
  int b = blockIdx.y;
  const float* x = base + (size_t)b * sstride;
  int c = threadIdx.x & 127;
  int rh = threadIdx.x >> 7;
  float acc = 0.f;
  for (int r = blockIdx.x * 2 + rh; r < n; r += gridDim.x * 2) {
    float v = x[(size_t)r * DD + c];
    acc += v * v;
  }
  __shared__ float red[256];
  red[threadIdx.x] = acc;
  __syncthreads();
  if (threadIdx.x < 128) atomicAdd(&sums[b * DD + threadIdx.x], red[threadIdx.x] + red[threadIdx.x + 128]);
}

__global__ void inv_k(const float* __restrict__ sums, float* __restrict__ inv, int n) {
  int i = blockIdx.x * blockDim.x + threadIdx.x;
  if (i < n) inv[i] = 1.f / fmaxf(sqrtf(sums[i]), EPSN);
}

__global__ __launch_bounds__(256) void scale_k(float* __restrict__ base, size_t slice_f4,
                                               const float* __restrict__ inv) {
  int b = blockIdx.y;
  float4* b4 = (float4*)base + (size_t)b * slice_f4;
  const float4* inv4 = (const float4*)inv + (size_t)b * 32;
  size_t stride = (size_t)blockDim.x * gridDim.x;
  for (size_t i = (size_t)blockIdx.x * blockDim.x + threadIdx.x; i < slice_f4; i += stride) {
    float4 s = inv4[i & 31];
    float4 v = b4[i];
    v.x *= s.x; v.y *= s.y; v.z *= s.z; v.w *= s.w;
    b4[i] = v;
  }
}

// ---------------- host ----------------
extern "C" void kernel_launch(void* const* d_in, const int* in_sizes, int n_in,
                              void* d_out, int out_size, void* d_ws, size_t ws_size,
                              hipStream_t stream) {
  const float* user_emb = (const float*)d_in[0];
  const float* item_emb = (const float*)d_in[1];
  const float* uu[4] = {(const float*)d_in[2], (const float*)d_in[4], (const float*)d_in[6], user_emb};
  const float* ii[4] = {(const float*)d_in[3], (const float*)d_in[5], (const float*)d_in[7], item_emb};
  const float* u_w = (const float*)d_in[8];
  const float* i_w = (const float*)d_in[9];
  EdgePtrs ep;
  for (int b = 0; b < 4; b++) {
    ep.rows[b] = (const int*)d_in[10 + 3 * b];
    ep.cols[b] = (const int*)d_in[11 + 3 * b];
    ep.vals[b] = (const float*)d_in[12 + 3 * b];
  }

  float* out = (float*)d_out;
  float* user_out = out;
  float* item_out = out + (size_t)NU * DD;
  float* l2nU = item_out + (size_t)NI * DD;
  float* l2nI = l2nU + (size_t)4 * NU * DD;
  float* u_slot[3];
  float* i_slot[3];
  {
    float* p = l2nI + (size_t)4 * NI * DD;
    for (int b = 0; b < 3; b++) {
      u_slot[b] = p; p += (size_t)NU * DD;
      i_slot[b] = p; p += (size_t)NI * DD;
    }
  }

  const size_t binsl = (size_t)2 * NNZ_E * 8;          // 32 MB per behavior slot
  const size_t item_bf_sz = (size_t)4 * NI * DD * 2;   // ~41 MB
  const size_t user_bf_sz = (size_t)4 * NU * DD * 2;   // ~82 MB
  const size_t smalls = 8u << 20;

  int batchB; bool bfI, bfU;
  if (ws_size >= 4 * binsl + item_bf_sz + user_bf_sz + smalls) { batchB = 4; bfI = bfU = true; }
  else if (ws_size >= 2 * binsl + item_bf_sz + user_bf_sz + smalls) { batchB = 2; bfI = bfU = true; }
  else if (ws_size >= binsl + item_bf_sz + user_bf_sz + smalls) { batchB = 1; bfI = bfU = true; }
  else if (ws_size >= binsl + item_bf_sz + smalls) { batchB = 1; bfI = true; bfU = false; }
  else { batchB = 1; bfI = bfU = false; }

  char* w = (char*)d_ws;
  auto alloc = [&](size_t bytes) {
    char* r = w;
    w += (bytes + 255) & ~(size_t)255;
    return r;
  };
  int2* binned = (int2*)alloc((size_t)batchB * binsl);
  unsigned short* itemB = bfI ? (unsigned short*)alloc(item_bf_sz) : nullptr;
  unsigned short* userB = bfU ? (unsigned short*)alloc(user_bf_sz) : nullptr;
  int* cntU = (int*)alloc((size_t)4 * NU * 4);
  int* cntI = (int*)alloc((size_t)4 * NI * 4);
  int* rpU = (int*)alloc((size_t)4 * (NU + 1) * 4);
  int* rpI = (int*)alloc((size_t)4 * (NI + 1) * 4);
  int* gcurA = (int*)alloc(4 * 2 * NBPAD * 4);
  float* colsums = (float*)alloc(8 * DD * 4);
  float* invs = (float*)alloc(8 * DD * 4);

  if (bfI)
    for (int b = 0; b < 4; b++)
      conv_k<<<512, 256, 0, stream>>>(ii[b], itemB + (size_t)b * NI * DD, NI * DD / 4);
  if (bfU)
    for (int b = 0; b < 4; b++)
      conv_k<<<512, 256, 0, stream>>>(uu[b], userB + (size_t)b * NU * DD, NU * DD / 4);

  hipMemsetAsync(cntU, 0, (size_t)4 * NU * 4, stream);
  hipMemsetAsync(cntI, 0, (size_t)4 * NI * 4, stream);
  hist_k<<<dim3(256, 4), 256, 0, stream>>>(ep, cntU, cntI);
  scan8_k<<<8, 1024, 0, stream>>>(cntU, cntI, rpU, rpI);

  const int nchunks = (NNZ_E + BIN_E - 1) / BIN_E;  // 245
  for (int b0 = 0; b0 < 4; b0 += batchB) {
    int tg = batchB * 2 * NBPAD;
    initg_k<<<(tg + 255) / 256, 256, 0, stream>>>(rpU, rpI, gcurA, b0, batchB);
    bin_k<<<dim3(nchunks, 2, batchB), 512, 0, stream>>>(ep, b0, gcurA, binned);
    sort2_k<<<batchB * (NBU + NBI), 512, 0, stream>>>(rpU, rpI, b0, binned);
    for (int j = 0; j < batchB; j++) {
      int b = b0 + j;
      const void* xt0 = bfI ? (const void*)(itemB + (size_t)b * NI * DD) : (const void*)ii[b];
      const void* xt1 = bfU ? (const void*)(userB + (size_t)b * NU * DD) : (const void*)uu[b];
      gather_k<<<10000, 256, 0, stream>>>(rpU + (size_t)b * (NU + 1),
                                          binned + ((size_t)j * 2 + 0) * NNZ_E, xt0, bfI ? 1 : 0,
                                          l2nU + (size_t)b * NU * DD, (b < 3) ? u_slot[b] : nullptr, NU);
      gather_k<<<5000, 256, 0, stream>>>(rpI + (size_t)b * (NI + 1),
                                         binned + ((size_t)j * 2 + 1) * NNZ_E, xt1, bfU ? 1 : 0,
                                         l2nI + (size_t)b * NI * DD, (b < 3) ? i_slot[b] : nullptr, NI);
    }
  }

  gemm_sig_k<<<NU / 64, 256, 0, stream>>>(l2nU, (size_t)NU * DD, u_w, user_out, NU);
  gemm_sig_k<<<NI / 64, 256, 0, stream>>>(l2nI, (size_t)NI * DD, i_w, item_out, NI);

  hipMemsetAsync(colsums, 0, 8 * DD * 4, stream);
  colsq_k<<<dim3(512, 4), 256, 0, stream>>>(l2nU, (size_t)NU * DD, NU, colsums);
  colsq_k<<<dim3(512, 4), 256, 0, stream>>>(l2nI, (size_t)NI * DD, NI, colsums + 4 * DD);
  inv_k<<<4, 256, 0, stream>>>(colsums, invs, 8 * DD);
  scale_k<<<dim3(1024, 4), 256, 0, stream>>>(l2nU, (size_t)NU * 32, invs);
  scale_k<<<dim3(1024, 4), 256, 0, stream>>>(l2nI, (size_t)NI * 32, invs + 4 * DD);
}

// Round 4
// 1397.630 us; speedup vs baseline: 8.6475x; 1.4374x over previous
//
#include <hip/hip_runtime.h>

#define NU 80000
#define NI 40000
#define DD 128
#define NNZ_E 2000000
#define EPSN 1e-12f
#define BWROWS 256
#define NBU 313   // ceil(NU/256)
#define NBI 157   // ceil(NI/256)
#define NBPAD 320
#define BSTRIDE 336
#define BIN_E 8192
#define S2CAP 16384

struct EdgePtrs { const int* rows[4]; const int* cols[4]; const float* vals[4]; };

__device__ inline unsigned short f2bf(float f) {
  unsigned int u = __float_as_uint(f);
  u += 0x7FFFu + ((u >> 16) & 1u);   // RNE
  return (unsigned short)(u >> 16);
}

__global__ __launch_bounds__(256) void conv_k(const float* __restrict__ src,
                                              unsigned short* __restrict__ dst, int n4) {
  int stride = blockDim.x * gridDim.x;
  for (int i = blockIdx.x * blockDim.x + threadIdx.x; i < n4; i += stride) {
    float4 f = ((const float4*)src)[i];
    ushort4 h;
    h.x = f2bf(f.x); h.y = f2bf(f.y); h.z = f2bf(f.z); h.w = f2bf(f.w);
    ((ushort4*)dst)[i] = h;
  }
}

// -------- bucket-level histogram (LDS-privatized), all behaviors --------
__global__ __launch_bounds__(256) void histB_k(EdgePtrs ep, int* cntA) {
  int b = blockIdx.y;
  const int* __restrict__ rows = ep.rows[b];
  const int* __restrict__ cols = ep.cols[b];
  __shared__ int lh[NBU + NBI];
  for (int i = threadIdx.x; i < NBU + NBI; i += blockDim.x) lh[i] = 0;
  __syncthreads();
  int stride = blockDim.x * gridDim.x;
  for (int e = blockIdx.x * blockDim.x + threadIdx.x; e < NNZ_E; e += stride) {
    atomicAdd(&lh[rows[e] >> 8], 1);
    atomicAdd(&lh[NBU + (cols[e] >> 8)], 1);
  }
  __syncthreads();
  int* cu = cntA + (b * 2 + 0) * NBPAD;
  int* ci = cntA + (b * 2 + 1) * NBPAD;
  for (int i = threadIdx.x; i < NBU + NBI; i += blockDim.x) {
    int v = lh[i];
    if (v) {
      if (i < NBU) atomicAdd(&cu[i], v);
      else atomicAdd(&ci[i - NBU], v);
    }
  }
}

// -------- bucket scan: 8 arrays of <=313 values --------
__global__ __launch_bounds__(512) void scanb_k(const int* cntA, int* baseA, int* gcurA) {
  __shared__ int wsums[9];
  int a = blockIdx.x;              // b*2 + dir
  int dir = a & 1;
  int n = dir ? NBI : NBU;
  const int* cnt = cntA + a * NBPAD;
  int* base = baseA + a * BSTRIDE;
  int* gcur = gcurA + a * NBPAD;
  int t = threadIdx.x, lane = t & 63, w = t >> 6;
  int v = (t < n) ? cnt[t] : 0;
  int s = v;
  #pragma unroll
  for (int off = 1; off < 64; off <<= 1) {
    int x = __shfl_up(s, off);
    if (lane >= off) s += x;
  }
  if (lane == 63) wsums[w] = s;
  __syncthreads();
  if (t == 0) {
    int run = 0;
    for (int k = 0; k < 8; k++) { int x = wsums[k]; wsums[k] = run; run += x; }
    wsums[8] = run;
  }
  __syncthreads();
  int ex = wsums[w] + s - v;
  if (t < n) { base[t] = ex; gcur[t] = ex; }
  if (t == 0) base[n] = wsums[8];
}

// -------- pass 1: counting-sort chunks by bucket, coalesced flush --------
__global__ __launch_bounds__(512) void bin_k(EdgePtrs ep, int b0, int* gcurA, int2* binned) {
  __shared__ int2 stage[BIN_E];     // 64 KB
  __shared__ int lh[NBPAD], lscan[NBPAD], lcur[NBPAD], gpos[NBPAD];
  __shared__ int wsums[9];
  int dir = blockIdx.y, j = blockIdx.z, b = b0 + j;
  int NB = dir ? NBI : NBU;
  const int* __restrict__ dst = dir ? ep.cols[b] : ep.rows[b];
  const int* __restrict__ src = dir ? ep.rows[b] : ep.cols[b];
  const float* __restrict__ vals = ep.vals[b];
  int* gcur = gcurA + (b * 2 + dir) * NBPAD;
  int2* out = binned + ((size_t)j * 2 + dir) * NNZ_E;
  int t = threadIdx.x;
  int e0 = blockIdx.x * BIN_E;
  int nh = min(BIN_E, NNZ_E - e0);
  for (int i = t; i < NBPAD; i += 512) lh[i] = 0;
  __syncthreads();
  for (int i = t; i < nh; i += 512) atomicAdd(&lh[dst[e0 + i] >> 8], 1);
  __syncthreads();
  {
    int lane = t & 63, w = t >> 6;
    int v = (t < NB) ? lh[t] : 0;
    int s = v;
    #pragma unroll
    for (int off = 1; off < 64; off <<= 1) {
      int x = __shfl_up(s, off);
      if (lane >= off) s += x;
    }
    if (lane == 63) wsums[w] = s;
    __syncthreads();
    if (t == 0) {
      int run = 0;
      for (int k = 0; k < 8; k++) { int x = wsums[k]; wsums[k] = run; run += x; }
      wsums[8] = run;
    }
    __syncthreads();
    int ex = wsums[w] + s - v;
    if (t < NB) { lscan[t] = ex; lcur[t] = ex; gpos[t] = atomicAdd(&gcur[t], v); }
  }
  __syncthreads();
  for (int i = t; i < nh; i += 512) {
    int d = dst[e0 + i], s = src[e0 + i];
    int k = d >> 8;
    int pos = atomicAdd(&lcur[k], 1);
    stage[pos] = make_int2(s | ((d & 255) << 17), __float_as_int(vals[e0 + i]));
  }
  __syncthreads();
  int w = t >> 6, lane = t & 63;
  for (int k = w; k < NB; k += 8) {
    int c = lh[k];
    const int2* sp = stage + lscan[k];
    int2* gp = out + gpos[k];
    for (int i = lane; i < c; i += 64) gp[i] = sp[i];
  }
}

// -------- pass 2: per-bucket exact-row sort + CSR row_ptr emission --------
__global__ __launch_bounds__(512) void sort3_k(int* rpU, int* rpI, int b0,
                                               const int* baseA, int2* binned) {
  __shared__ int2 stage[S2CAP];   // 128 KB
  __shared__ int lh[256];
  __shared__ int excl[257];
  __shared__ int lcur[256];
  __shared__ int wsums[5];
  int gb = blockIdx.x;
  int j = gb / (NBU + NBI);
  int r = gb - j * (NBU + NBI);
  int dir = (r >= NBU) ? 1 : 0;
  int k = dir ? (r - NBU) : r;
  int b = b0 + j;
  int n = dir ? NI : NU;
  int* rp = dir ? (rpI + (size_t)b * (NI + 1)) : (rpU + (size_t)b * (NU + 1));
  const int* base = baseA + (b * 2 + dir) * BSTRIDE;
  int2* bb = binned + ((size_t)j * 2 + dir) * NNZ_E;
  int row0 = k << 8;
  int nrows = min(BWROWS, n - row0);
  int base0 = base[k];
  int tot = base[k + 1] - base0;
  int t = threadIdx.x;
  if (t < 256) lh[t] = 0;
  __syncthreads();
  for (int i = t; i < tot; i += 512) atomicAdd(&lh[(bb[base0 + i].x >> 17) & 255], 1);
  __syncthreads();
  int v = 0, s = 0;
  if (t < 256) {
    int lane = t & 63, w = t >> 6;
    v = lh[t]; s = v;
    #pragma unroll
    for (int off = 1; off < 64; off <<= 1) {
      int x = __shfl_up(s, off);
      if (lane >= off) s += x;
    }
    if (lane == 63) wsums[w] = s;
  }
  __syncthreads();
  if (t == 0) {
    int run = 0;
    for (int q = 0; q < 4; q++) { int x = wsums[q]; wsums[q] = run; run += x; }
    wsums[4] = run;
  }
  __syncthreads();
  if (t < 256) {
    int ex = wsums[t >> 6] + s - v;
    excl[t] = ex; lcur[t] = ex;
  }
  if (t == 0) excl[256] = wsums[4];
  __syncthreads();
  if (t <= nrows) rp[row0 + t] = base0 + excl[t];
  for (int i = t; i < tot; i += 512) {
    int2 p = bb[base0 + i];
    int ld = (p.x >> 17) & 255;
    int pos = atomicAdd(&lcur[ld], 1);
    stage[pos] = make_int2(p.x & 0x1FFFF, p.y);
  }
  __syncthreads();
  for (int i = t; i < tot; i += 512) bb[base0 + i] = stage[i];
}

// -------- gather SpMM: one 32-lane group per dst row, register acc --------
__global__ __launch_bounds__(256) void gather_k(const int* __restrict__ rp, const int2* __restrict__ pairs,
                                                const void* __restrict__ xt, int isbf,
                                                float* __restrict__ out1, float* __restrict__ out2,
                                                int nrows) {
  int gid = blockIdx.x * 8 + (threadIdx.x >> 5);
  int lane = threadIdx.x & 31;
  int tot = gridDim.x * 8;
  for (int r = gid; r < nrows; r += tot) {
    int beg = rp[r], end = rp[r + 1];
    float4 a0 = make_float4(0.f, 0.f, 0.f, 0.f);
    float4 a1 = make_float4(0.f, 0.f, 0.f, 0.f);
    int e = beg;
    if (isbf) {
      const ushort4* __restrict__ x4 = (const ushort4*)xt;
      for (; e + 3 < end; e += 4) {
        int2 p0 = pairs[e], p1 = pairs[e + 1], p2 = pairs[e + 2], p3 = pairs[e + 3];
        ushort4 h0 = x4[(size_t)p0.x * 32 + lane];
        ushort4 h1 = x4[(size_t)p1.x * 32 + lane];
        ushort4 h2 = x4[(size_t)p2.x * 32 + lane];
        ushort4 h3 = x4[(size_t)p3.x * 32 + lane];
        float v0 = __int_as_float(p0.y), v1 = __int_as_float(p1.y);
        float v2 = __int_as_float(p2.y), v3 = __int_as_float(p3.y);
        a0.x += v0 * __uint_as_float((unsigned)h0.x << 16);
        a0.y += v0 * __uint_as_float((unsigned)h0.y << 16);
        a0.z += v0 * __uint_as_float((unsigned)h0.z << 16);
        a0.w += v0 * __uint_as_float((unsigned)h0.w << 16);
        a1.x += v1 * __uint_as_float((unsigned)h1.x << 16);
        a1.y += v1 * __uint_as_float((unsigned)h1.y << 16);
        a1.z += v1 * __uint_as_float((unsigned)h1.z << 16);
        a1.w += v1 * __uint_as_float((unsigned)h1.w << 16);
        a0.x += v2 * __uint_as_float((unsigned)h2.x << 16);
        a0.y += v2 * __uint_as_float((unsigned)h2.y << 16);
        a0.z += v2 * __uint_as_float((unsigned)h2.z << 16);
        a0.w += v2 * __uint_as_float((unsigned)h2.w << 16);
        a1.x += v3 * __uint_as_float((unsigned)h3.x << 16);
        a1.y += v3 * __uint_as_float((unsigned)h3.y << 16);
        a1.z += v3 * __uint_as_float((unsigned)h3.z << 16);
        a1.w += v3 * __uint_as_float((unsigned)h3.w << 16);
      }
      for (; e < end; e++) {
        int2 p = pairs[e];
        ushort4 h = x4[(size_t)p.x * 32 + lane];
        float v = __int_as_float(p.y);
        a0.x += v * __uint_as_float((unsigned)h.x << 16);
        a0.y += v * __uint_as_float((unsigned)h.y << 16);
        a0.z += v * __uint_as_float((unsigned)h.z << 16);
        a0.w += v * __uint_as_float((unsigned)h.w << 16);
      }
    } else {
      const float4* __restrict__ x4 = (const float4*)xt;
      for (; e + 3 < end; e += 4) {
        int2 p0 = pairs[e], p1 = pairs[e + 1], p2 = pairs[e + 2], p3 = pairs[e + 3];
        float4 x0 = x4[(size_t)p0.x * 32 + lane];
        float4 x1 = x4[(size_t)p1.x * 32 + lane];
        float4 x2 = x4[(size_t)p2.x * 32 + lane];
        float4 x3 = x4[(size_t)p3.x * 32 + lane];
        float v0 = __int_as_float(p0.y), v1 = __int_as_float(p1.y);
        float v2 = __int_as_float(p2.y), v3 = __int_as_float(p3.y);
        a0.x += v0 * x0.x; a0.y += v0 * x0.y; a0.z += v0 * x0.z; a0.w += v0 * x0.w;
        a1.x += v1 * x1.x; a1.y += v1 * x1.y; a1.z += v1 * x1.z; a1.w += v1 * x1.w;
        a0.x += v2 * x2.x; a0.y += v2 * x2.y; a0.z += v2 * x2.z; a0.w += v2 * x2.w;
        a1.x += v3 * x3.x; a1.y += v3 * x3.y; a1.z += v3 * x3.z; a1.w += v3 * x3.w;
      }
      for (; e < end; e++) {
        int2 p = pairs[e];
        float4 xv = x4[(size_t)p.x * 32 + lane];
        float v = __int_as_float(p.y);
        a0.x += v * xv.x; a0.y += v * xv.y; a0.z += v * xv.z; a0.w += v * xv.w;
      }
    }
    float4 res = make_float4(a0.x + a1.x, a0.y + a1.y, a0.z + a1.z, a0.w + a1.w);
    ((float4*)out1)[(size_t)r * 32 + lane] = res;
    if (out2) ((float4*)out2)[(size_t)r * 32 + lane] = res;
  }
}

// ---------------- mean(4 slices) @ W, sigmoid ----------------
__global__ __launch_bounds__(256) void gemm_sig_k(const float* __restrict__ x, size_t sstride,
                                                  const float* __restrict__ W, float* __restrict__ out,
                                                  int n) {
  __shared__ float wl[DD * DD];
  __shared__ float rl[8][DD];
  for (int i = threadIdx.x; i < DD * DD / 4; i += blockDim.x)
    ((float4*)wl)[i] = ((const float4*)W)[i];
  int c = threadIdx.x & 127;
  int g = threadIdx.x >> 7;
  int row0 = blockIdx.x * 64;
  for (int rr = 0; rr < 64; rr += 8) {
    int rbase = row0 + rr;
    __syncthreads();
    for (int i = threadIdx.x; i < 8 * DD; i += blockDim.x) {
      int lr = i >> 7, lc = i & 127;
      int r = rbase + lr;
      float m = 0.f;
      if (r < n) {
        size_t off = (size_t)r * DD + lc;
        m = 0.25f * (x[off] + x[off + sstride] + x[off + 2 * sstride] + x[off + 3 * sstride]);
      }
      rl[lr][lc] = m;
    }
    __syncthreads();
    float acc0 = 0.f, acc1 = 0.f, acc2 = 0.f, acc3 = 0.f;
    #pragma unroll 4
    for (int k = 0; k < DD; k++) {
      float wv = wl[k * DD + c];
      acc0 += rl[g * 4 + 0][k] * wv;
      acc1 += rl[g * 4 + 1][k] * wv;
      acc2 += rl[g * 4 + 2][k] * wv;
      acc3 += rl[g * 4 + 3][k] * wv;
    }
    float accs[4] = {acc0, acc1, acc2, acc3};
    for (int jj = 0; jj < 4; jj++) {
      int r = rbase + g * 4 + jj;
      if (r < n) out[(size_t)r * DD + c] = 1.f / (1.f + __expf(-accs[jj]));
    }
  }
}

// ---------------- column sum-of-squares / normalize ----------------
__global__ __launch_bounds__(256) void colsq_k(const float* __restrict__ base, size_t sstride, int n,
                                               float* __restrict__ sums) {
  int b = blockIdx.y;
  const float* x = base + (size_t)b * sstride;
  int c = threadIdx.x & 127;
  int rh = threadIdx.x >> 7;
  float acc = 0.f;
  for (int r = blockIdx.x * 2 + rh; r < n; r += gridDim.x * 2) {
    float v = x[(size_t)r * DD + c];
    acc += v * v;
  }
  __shared__ float red[256];
  red[threadIdx.x] = acc;
  __syncthreads();
  if (threadIdx.x < 128) atomicAdd(&sums[b * DD + threadIdx.x], red[threadIdx.x] + red[threadIdx.x + 128]);
}

__global__ void inv_k(const float* __restrict__ sums, float* __restrict__ inv, int n) {
  int i = blockIdx.x * blockDim.x + threadIdx.x;
  if (i < n) inv[i] = 1.f / fmaxf(sqrtf(sums[i]), EPSN);
}

__global__ __launch_bounds__(256) void scale_k(float* __restrict__ base, size_t slice_f4,
                                               const float* __restrict__ inv) {
  int b = blockIdx.y;
  float4* b4 = (float4*)base + (size_t)b * slice_f4;
  const float4* inv4 = (const float4*)inv + (size_t)b * 32;
  size_t stride = (size_t)blockDim.x * gridDim.x;
  for (size_t i = (size_t)blockIdx.x * blockDim.x + threadIdx.x; i < slice_f4; i += stride) {
    float4 s = inv4[i & 31];
    float4 v = b4[i];
    v.x *= s.x; v.y *= s.y; v.z *= s.z; v.w *= s.w;
    b4[i] = v;
  }
}

// ---------------- host ----------------
extern "C" void kernel_launch(void* const* d_in, const int* in_sizes, int n_in,
                              void* d_out, int out_size, void* d_ws, size_t ws_size,
                              hipStream_t stream) {
  const float* user_emb = (const float*)d_in[0];
  const float* item_emb = (const float*)d_in[1];
  const float* uu[4] = {(const float*)d_in[2], (const float*)d_in[4], (const float*)d_in[6], user_emb};
  const float* ii[4] = {(const float*)d_in[3], (const float*)d_in[5], (const float*)d_in[7], item_emb};
  const float* u_w = (const float*)d_in[8];
  const float* i_w = (const float*)d_in[9];
  EdgePtrs ep;
  for (int b = 0; b < 4; b++) {
    ep.rows[b] = (const int*)d_in[10 + 3 * b];
    ep.cols[b] = (const int*)d_in[11 + 3 * b];
    ep.vals[b] = (const float*)d_in[12 + 3 * b];
  }

  float* out = (float*)d_out;
  float* user_out = out;
  float* item_out = out + (size_t)NU * DD;
  float* l2nU = item_out + (size_t)NI * DD;
  float* l2nI = l2nU + (size_t)4 * NU * DD;
  float* u_slot[3];
  float* i_slot[3];
  {
    float* p = l2nI + (size_t)4 * NI * DD;
    for (int b = 0; b < 3; b++) {
      u_slot[b] = p; p += (size_t)NU * DD;
      i_slot[b] = p; p += (size_t)NI * DD;
    }
  }

  const size_t binsl = (size_t)2 * NNZ_E * 8;          // 32 MB per behavior slot
  const size_t item_bf_sz = (size_t)4 * NI * DD * 2;   // ~41 MB
  const size_t user_bf_sz = (size_t)4 * NU * DD * 2;   // ~82 MB
  const size_t smalls = 8u << 20;

  int batchB; bool bfI, bfU;
  if (ws_size >= 4 * binsl + item_bf_sz + user_bf_sz + smalls) { batchB = 4; bfI = bfU = true; }
  else if (ws_size >= 2 * binsl + item_bf_sz + user_bf_sz + smalls) { batchB = 2; bfI = bfU = true; }
  else if (ws_size >= binsl + item_bf_sz + user_bf_sz + smalls) { batchB = 1; bfI = bfU = true; }
  else if (ws_size >= binsl + item_bf_sz + smalls) { batchB = 1; bfI = true; bfU = false; }
  else { batchB = 1; bfI = bfU = false; }

  char* w = (char*)d_ws;
  auto alloc = [&](size_t bytes) {
    char* r = w;
    w += (bytes + 255) & ~(size_t)255;
    return r;
  };
  int2* binned = (int2*)alloc((size_t)batchB * binsl);
  unsigned short* itemB = bfI ? (unsigned short*)alloc(item_bf_sz) : nullptr;
  unsigned short* userB = bfU ? (unsigned short*)alloc(user_bf_sz) : nullptr;
  int* cntA = (int*)alloc(4 * 2 * NBPAD * 4);
  int* baseA = (int*)alloc(4 * 2 * BSTRIDE * 4);
  int* gcurA = (int*)alloc(4 * 2 * NBPAD * 4);
  int* rpU = (int*)alloc((size_t)4 * (NU + 1) * 4);
  int* rpI = (int*)alloc((size_t)4 * (NI + 1) * 4);
  float* colsums = (float*)alloc(8 * DD * 4);
  float* invs = (float*)alloc(8 * DD * 4);

  if (bfI)
    for (int b = 0; b < 4; b++)
      conv_k<<<512, 256, 0, stream>>>(ii[b], itemB + (size_t)b * NI * DD, NI * DD / 4);
  if (bfU)
    for (int b = 0; b < 4; b++)
      conv_k<<<512, 256, 0, stream>>>(uu[b], userB + (size_t)b * NU * DD, NU * DD / 4);

  hipMemsetAsync(cntA, 0, 4 * 2 * NBPAD * 4, stream);
  histB_k<<<dim3(256, 4), 256, 0, stream>>>(ep, cntA);
  scanb_k<<<8, 512, 0, stream>>>(cntA, baseA, gcurA);

  const int nchunks = (NNZ_E + BIN_E - 1) / BIN_E;  // 245
  for (int b0 = 0; b0 < 4; b0 += batchB) {
    bin_k<<<dim3(nchunks, 2, batchB), 512, 0, stream>>>(ep, b0, gcurA, binned);
    sort3_k<<<batchB * (NBU + NBI), 512, 0, stream>>>(rpU, rpI, b0, baseA, binned);
    for (int j = 0; j < batchB; j++) {
      int b = b0 + j;
      const void* xt0 = bfI ? (const void*)(itemB + (size_t)b * NI * DD) : (const void*)ii[b];
      const void* xt1 = bfU ? (const void*)(userB + (size_t)b * NU * DD) : (const void*)uu[b];
      gather_k<<<10000, 256, 0, stream>>>(rpU + (size_t)b * (NU + 1),
                                          binned + ((size_t)j * 2 + 0) * NNZ_E, xt0, bfI ? 1 : 0,
                                          l2nU + (size_t)b * NU * DD, (b < 3) ? u_slot[b] : nullptr, NU);
      gather_k<<<5000, 256, 0, stream>>>(rpI + (size_t)b * (NI + 1),
                                         binned + ((size_t)j * 2 + 1) * NNZ_E, xt1, bfU ? 1 : 0,
                                         l2nI + (size_t)b * NI * DD, (b < 3) ? i_slot[b] : nullptr, NI);
    }
  }

  gemm_sig_k<<<NU / 64, 256, 0, stream>>>(l2nU, (size_t)NU * DD, u_w, user_out, NU);
  gemm_sig_k<<<NI / 64, 256, 0, stream>>>(l2nI, (size_t)NI * DD, i_w, item_out, NI);

  hipMemsetAsync(colsums, 0, 8 * DD * 4, stream);
  colsq_k<<<dim3(512, 4), 256, 0, stream>>>(l2nU, (size_t)NU * DD, NU, colsums);
  colsq_k<<<dim3(512, 4), 256, 0, stream>>>(l2nI, (size_t)NI * DD, NI, colsums + 4 * DD);
  inv_k<<<4, 256, 0, stream>>>(colsums, invs, 8 * DD);
  scale_k<<<dim3(1024, 4), 256, 0, stream>>>(l2nU, (size_t)NU * 32, invs);
  scale_k<<<dim3(1024, 4), 256, 0, stream>>>(l2nI, (size_t)NI * 32, invs + 4 * DD);
}